// Round 1
// 532.809 us; speedup vs baseline: 1.1620x; 1.1620x over previous
//
#include <hip/hip_runtime.h>
#include <stdint.h>

// Problem: ComplexDepthwiseBatchNorm  N=16384, C=8, F=257
// Layout: x[N][C*F] row-major; NCOLS = 2056 columns per row.
// Dtype of x / W / out is detected ON DEVICE (bf16 vs fp32) — see detect_kernel.
#define NROWS   16384
#define NCOLS   2056
#define NG      257          // groups of 8 elements per row (2056/8)
#define EPSV    1e-6f
#define DELTA_MAX 1e8f
#define SR      64           // row slices for stats (NROWS/SR = 256 rows/slice)

typedef float    f32x4 __attribute__((ext_vector_type(4)));
typedef uint32_t u32x4 __attribute__((ext_vector_type(4)));

__device__ __forceinline__ float bf_lo(uint32_t u) {
    return __builtin_bit_cast(float, u << 16);
}
__device__ __forceinline__ float bf_hi(uint32_t u) {
    return __builtin_bit_cast(float, u & 0xffff0000u);
}
__device__ __forceinline__ float bf1(uint16_t u) {
    return __builtin_bit_cast(float, (uint32_t)u << 16);
}
// round-to-nearest-even bf16 pair pack: lo -> bits[15:0], hi -> bits[31:16]
__device__ __forceinline__ uint32_t bf16pair(float lo, float hi) {
    uint32_t ul = __builtin_bit_cast(uint32_t, lo);
    uint32_t uh = __builtin_bit_cast(uint32_t, hi);
    ul = (ul + 0x7fffu + ((ul >> 16) & 1u)) >> 16;
    uh = (uh + 0x7fffu + ((uh >> 16) & 1u)) & 0xffff0000u;
    return ul | uh;
}

// ---------------- Pass 0: dtype detection ----------------
// flags[0]=1 iff x is fp32; flags[1]=1 iff W/B are fp32.
__global__ __launch_bounds__(512) void detect_kernel(
    const uint32_t* __restrict__ xr_u, const uint32_t* __restrict__ wrr_u,
    int* __restrict__ flags)
{
    __shared__ int cnt[2];
    if (threadIdx.x < 2) cnt[threadIdx.x] = 0;
    __syncthreads();
    const int part = threadIdx.x >> 8;                    // 0: x, 1: Wrr
    const uint32_t u = part ? wrr_u[threadIdx.x & 255] : xr_u[threadIdx.x & 255];
    const uint32_t e = (u >> 7) & 0xFFu;
    const int ok = (e >= 100u && e <= 131u) ? 1 : 0;
    atomicAdd(&cnt[part], ok);
    __syncthreads();
    if (threadIdx.x == 0) {
        flags[0] = (cnt[0] < 128) ? 1 : 0;
        flags[1] = (cnt[1] < 128) ? 1 : 0;
    }
}

// ---------------- stat accumulation helpers ----------------
// acc layout: acc[stat*8 + colj], stats: 0=sr 1=si 2=srr 3=sri 4=sii
__device__ __forceinline__ void accum_bf16x8(float* acc, uint4 a, uint4 b) {
    const uint32_t au[4] = {a.x, a.y, a.z, a.w};
    const uint32_t bu[4] = {b.x, b.y, b.z, b.w};
    #pragma unroll
    for (int j = 0; j < 4; ++j) {
        const float r0 = bf_lo(au[j]), r1 = bf_hi(au[j]);
        const float i0 = bf_lo(bu[j]), i1 = bf_hi(bu[j]);
        acc[0*8 + 2*j]     += r0;       acc[1*8 + 2*j]     += i0;
        acc[2*8 + 2*j]     += r0*r0;    acc[3*8 + 2*j]     += r0*i0;
        acc[4*8 + 2*j]     += i0*i0;
        acc[0*8 + 2*j + 1] += r1;       acc[1*8 + 2*j + 1] += i1;
        acc[2*8 + 2*j + 1] += r1*r1;    acc[3*8 + 2*j + 1] += r1*i1;
        acc[4*8 + 2*j + 1] += i1*i1;
    }
}
__device__ __forceinline__ void accum_f32x8(float* acc, float4 a0, float4 a1,
                                            float4 b0, float4 b1) {
    const float xr[8] = {a0.x,a0.y,a0.z,a0.w,a1.x,a1.y,a1.z,a1.w};
    const float xi[8] = {b0.x,b0.y,b0.z,b0.w,b1.x,b1.y,b1.z,b1.w};
    #pragma unroll
    for (int j = 0; j < 8; ++j) {
        acc[0*8 + j] += xr[j];        acc[1*8 + j] += xi[j];
        acc[2*8 + j] += xr[j]*xr[j];  acc[3*8 + j] += xr[j]*xi[j];
        acc[4*8 + j] += xi[j]*xi[j];
    }
}

// ---------------- Pass 1: per-column sums (tile-stationary) ----------------
// grid dim3(SR, 33) x block 256.
//   blockIdx.x = rs (row slice, 256 rows), blockIdx.y = ct (column tile).
//   ct < 32 : block owns column groups [8ct, 8ct+8). thread t: group = 8ct+(t&7),
//             row-lane = t>>3 (32 lanes/group), 8 rows each.
//             Lanes 0-7 read 128 B contiguous -> full-line requests.
//   ct == 32: leftover group 256; thread t owns row rbase+t (1 load).
// Reduction: shfl_xor over row-lanes -> LDS combine over 4 waves ->
//            320 atomics/block (was 10240 thread-atomics' worth).
// Note: adjacent ct tiles (which share row-misaligned cache lines) are 64
// dispatch-indices apart => same XCD under %8 round-robin => L2 line sharing.
__global__ __launch_bounds__(256) void stats_kernel(
    const void* __restrict__ xr_p, const void* __restrict__ xi_p,
    const int* __restrict__ flags, float* __restrict__ sums)
{
    const int rs = blockIdx.x;          // 0..SR-1
    const int ct = blockIdx.y;          // 0..32
    const int t  = threadIdx.x;
    const int rbase = rs * (NROWS / SR);   // 256 rows per slice

    float acc[40];
    #pragma unroll
    for (int j = 0; j < 40; ++j) acc[j] = 0.f;

    const bool isfp32 = (flags[0] != 0);

    if (ct < 32) {
        const int grp = ct * 8 + (t & 7);
        const int rl  = t >> 3;             // 0..31
        if (!isfp32) {
            const uint4* xr4 = (const uint4*)xr_p;
            const uint4* xi4 = (const uint4*)xi_p;
            #pragma unroll 2
            for (int k = 0; k < 8; ++k) {
                const size_t g = (size_t)(rbase + rl + 32*k) * NG + grp;
                accum_bf16x8(acc, xr4[g], xi4[g]);
            }
        } else {
            const float4* xr4 = (const float4*)xr_p;
            const float4* xi4 = (const float4*)xi_p;
            #pragma unroll 2
            for (int k = 0; k < 8; ++k) {
                const size_t g = (size_t)(rbase + rl + 32*k) * 514 + 2*grp;
                accum_f32x8(acc, xr4[g], xr4[g+1], xi4[g], xi4[g+1]);
            }
        }
        // reduce over the 8 row-lanes sharing this group (lane bits 3..5)
        #pragma unroll
        for (int j = 0; j < 40; ++j) acc[j] += __shfl_xor(acc[j], 8, 64);
        #pragma unroll
        for (int j = 0; j < 40; ++j) acc[j] += __shfl_xor(acc[j], 16, 64);
        #pragma unroll
        for (int j = 0; j < 40; ++j) acc[j] += __shfl_xor(acc[j], 32, 64);
    } else {
        // leftover group 256 (columns 2048..2055): one row per thread
        if (!isfp32) {
            const uint4* xr4 = (const uint4*)xr_p;
            const uint4* xi4 = (const uint4*)xi_p;
            const size_t g = (size_t)(rbase + t) * NG + 256;
            accum_bf16x8(acc, xr4[g], xi4[g]);
        } else {
            const float4* xr4 = (const float4*)xr_p;
            const float4* xi4 = (const float4*)xi_p;
            const size_t g = (size_t)(rbase + t) * 514 + 512;
            accum_f32x8(acc, xr4[g], xr4[g+1], xi4[g], xi4[g+1]);
        }
        // full 64-lane reduction
        #pragma unroll
        for (int m = 1; m <= 32; m <<= 1) {
            #pragma unroll
            for (int j = 0; j < 40; ++j) acc[j] += __shfl_xor(acc[j], m, 64);
        }
    }

    // cross-wave combine: per-wave representatives -> LDS -> sum 4 -> atomic
    __shared__ float red[4][320];
    const int wv = t >> 6, ln = t & 63;
    if (ct < 32) {
        if (ln < 8) {
            #pragma unroll
            for (int j = 0; j < 40; ++j) red[wv][ln*40 + j] = acc[j];
        }
    } else {
        if (ln == 0) {
            #pragma unroll
            for (int j = 0; j < 40; ++j) red[wv][j] = acc[j];
        }
    }
    __syncthreads();
    const int nvals = (ct < 32) ? 320 : 40;
    for (int idx = t; idx < nvals; idx += 256) {
        const float v = red[0][idx] + red[1][idx] + red[2][idx] + red[3][idx];
        const int gi  = idx / 40;
        const int j   = idx - gi * 40;          // stat*8 + colj
        const int col = (ct * 8 + gi) * 8 + (j & 7);
        atomicAdd(&sums[(j >> 3) * NCOLS + col], v);
    }
}

// ---------------- Pass 2: sums -> per-column coefficients ----------------
__global__ __launch_bounds__(256) void coef_kernel(
    const float* __restrict__ sums,
    const void* __restrict__ Wrr_p, const void* __restrict__ Wri_p,
    const void* __restrict__ Wii_p, const void* __restrict__ Br_p,
    const void* __restrict__ Bi_p,
    const int* __restrict__ flags, float* __restrict__ coef)
{
    const int j = blockIdx.x * 256 + threadIdx.x;
    if (j >= NCOLS) return;
    const float invN = 1.0f / (float)NROWS;
    const float Mr  = sums[0*NCOLS+j] * invN;
    const float Mi  = sums[1*NCOLS+j] * invN;
    const float Vrr = sums[2*NCOLS+j] * invN - Mr * Mr;
    const float Vri = sums[3*NCOLS+j] * invN - Mr * Mi;
    const float Vii = sums[4*NCOLS+j] * invN - Mi * Mi;
    const float tau   = Vrr + Vii;
    const float delta = fminf(fmaxf(Vrr * Vii - Vri * Vri, EPSV), DELTA_MAX);
    const float s   = sqrtf(delta);
    const float t   = sqrtf(tau + 2.0f * s);
    const float rst = 1.0f / (s * t);
    const float Urr = (s + Vii) * rst;
    const float Uii = (s + Vrr) * rst;
    const float Uri = -Vri * rst;

    float wrr, wri, wii, br, bi;
    if (flags[1]) {
        wrr = ((const float*)Wrr_p)[j];  wri = ((const float*)Wri_p)[j];
        wii = ((const float*)Wii_p)[j];
        br  = ((const float*)Br_p)[j];   bi  = ((const float*)Bi_p)[j];
    } else {
        wrr = bf1(((const uint16_t*)Wrr_p)[j]);  wri = bf1(((const uint16_t*)Wri_p)[j]);
        wii = bf1(((const uint16_t*)Wii_p)[j]);
        br  = bf1(((const uint16_t*)Br_p)[j]);   bi  = bf1(((const uint16_t*)Bi_p)[j]);
    }
    const float Zrr = wrr * Urr + wri * Uri;
    const float Zri = wrr * Uri + wri * Uii;
    const float Zir = wri * Urr + wii * Uri;
    const float Zii = wri * Uri + wii * Uii;
    coef[0*NCOLS+j] = Zrr;
    coef[1*NCOLS+j] = Zri;
    coef[2*NCOLS+j] = Zir;
    coef[3*NCOLS+j] = Zii;
    coef[4*NCOLS+j] = br - Zrr * Mr - Zri * Mi;
    coef[5*NCOLS+j] = bi - Zir * Mr - Zii * Mi;
}

// ---------------- Pass 3: apply (column-stationary, coeffs in regs) ----------
// grid 2056 x block 256 => T = 526336 = 2048*257 (bijection tid->(r0,c)).
// Flat-contiguous: g = r0*257 + c = tid, so loads/stores are fully coalesced.
// r0 in [0,2048), 8 iterations. Occupancy ~8224 waves (was 2056 -> 25%).
// Output stores are non-temporal: y is never re-read; keeps x in L3.
__global__ __launch_bounds__(256) void apply_kernel(
    const void* __restrict__ xr_p, const void* __restrict__ xi_p,
    const float* __restrict__ coef, const int* __restrict__ flags,
    void* __restrict__ out_p)
{
    const int tid = blockIdx.x * 256 + threadIdx.x;
    const int c  = tid % NG;
    const int r0 = tid / NG;            // [0,2048)
    const int col = c * 8;

    float Z[6][8];
    #pragma unroll
    for (int t = 0; t < 6; ++t) {
        const float4 lo = *(const float4*)(coef + t*NCOLS + col);
        const float4 hi = *(const float4*)(coef + t*NCOLS + col + 4);
        Z[t][0]=lo.x; Z[t][1]=lo.y; Z[t][2]=lo.z; Z[t][3]=lo.w;
        Z[t][4]=hi.x; Z[t][5]=hi.y; Z[t][6]=hi.z; Z[t][7]=hi.w;
    }

    if (flags[0]) {
        // -------- fp32 path --------
        const float4* xr4 = (const float4*)xr_p;
        const float4* xi4 = (const float4*)xi_p;
        f32x4* yr4 = (f32x4*)out_p;
        f32x4* yi4 = yr4 + (size_t)NROWS * 514;   // yi after N*C*F floats
        #pragma unroll 2
        for (int k = 0; k < 8; ++k) {
            const size_t g = (size_t)(r0 + (k << 11)) * 514 + 2 * c;
            const float4 a0 = xr4[g], a1 = xr4[g + 1];
            const float4 b0 = xi4[g], b1 = xi4[g + 1];
            const float xrv[8] = {a0.x,a0.y,a0.z,a0.w,a1.x,a1.y,a1.z,a1.w};
            const float xiv[8] = {b0.x,b0.y,b0.z,b0.w,b1.x,b1.y,b1.z,b1.w};
            float yrv[8], yiv[8];
            #pragma unroll
            for (int j = 0; j < 8; ++j) {
                yrv[j] = Z[0][j]*xrv[j] + Z[1][j]*xiv[j] + Z[4][j];
                yiv[j] = Z[2][j]*xrv[j] + Z[3][j]*xiv[j] + Z[5][j];
            }
            const f32x4 s0 = {yrv[0], yrv[1], yrv[2], yrv[3]};
            const f32x4 s1 = {yrv[4], yrv[5], yrv[6], yrv[7]};
            const f32x4 t0 = {yiv[0], yiv[1], yiv[2], yiv[3]};
            const f32x4 t1 = {yiv[4], yiv[5], yiv[6], yiv[7]};
            __builtin_nontemporal_store(s0, yr4 + g);
            __builtin_nontemporal_store(s1, yr4 + g + 1);
            __builtin_nontemporal_store(t0, yi4 + g);
            __builtin_nontemporal_store(t1, yi4 + g + 1);
        }
    } else {
        // -------- bf16 path --------
        const uint4* xr4 = (const uint4*)xr_p;
        const uint4* xi4 = (const uint4*)xi_p;
        u32x4* yr4 = (u32x4*)out_p;
        u32x4* yi4 = yr4 + (size_t)NROWS * NG;     // yi after N*C*F bf16
        #pragma unroll 2
        for (int k = 0; k < 8; ++k) {
            const size_t g = (size_t)(r0 + (k << 11)) * NG + c;
            const uint4 a = xr4[g];
            const uint4 b = xi4[g];
            const uint32_t au[4] = {a.x, a.y, a.z, a.w};
            const uint32_t bu[4] = {b.x, b.y, b.z, b.w};
            uint32_t ou[4], pu[4];
            #pragma unroll
            for (int j = 0; j < 4; ++j) {
                const int e0 = 2*j, e1 = 2*j + 1;
                const float xr0 = bf_lo(au[j]), xr1 = bf_hi(au[j]);
                const float xi0 = bf_lo(bu[j]), xi1 = bf_hi(bu[j]);
                const float yr0 = Z[0][e0]*xr0 + Z[1][e0]*xi0 + Z[4][e0];
                const float yi0 = Z[2][e0]*xr0 + Z[3][e0]*xi0 + Z[5][e0];
                const float yr1 = Z[0][e1]*xr1 + Z[1][e1]*xi1 + Z[4][e1];
                const float yi1 = Z[2][e1]*xr1 + Z[3][e1]*xi1 + Z[5][e1];
                ou[j] = bf16pair(yr0, yr1);
                pu[j] = bf16pair(yi0, yi1);
            }
            const u32x4 o = {ou[0], ou[1], ou[2], ou[3]};
            const u32x4 p = {pu[0], pu[1], pu[2], pu[3]};
            __builtin_nontemporal_store(o, yr4 + g);
            __builtin_nontemporal_store(p, yi4 + g);
        }
    }
}

extern "C" void kernel_launch(void* const* d_in, const int* in_sizes, int n_in,
                              void* d_out, int out_size, void* d_ws, size_t ws_size,
                              hipStream_t stream)
{
    const void* xr_p = d_in[0];
    const void* xi_p = d_in[1];
    const void* Wrr  = d_in[2];
    const void* Wri  = d_in[3];
    const void* Wii  = d_in[4];
    const void* Br   = d_in[5];
    const void* Bi   = d_in[6];

    float* sums  = (float*)d_ws;             // 5 * 2056 f32
    float* coef  = sums + 5 * NCOLS;         // 6 * 2056 f32
    int*   flags = (int*)(coef + 6 * NCOLS); // 2 ints

    detect_kernel<<<1, 512, 0, stream>>>((const uint32_t*)xr_p, (const uint32_t*)Wrr, flags);
    hipMemsetAsync(sums, 0, 5 * NCOLS * sizeof(float), stream);
    stats_kernel<<<dim3(SR, 33), 256, 0, stream>>>(xr_p, xi_p, flags, sums);
    coef_kernel<<<(NCOLS + 255) / 256, 256, 0, stream>>>(sums, Wrr, Wri, Wii, Br, Bi, flags, coef);
    apply_kernel<<<2056, 256, 0, stream>>>(xr_p, xi_p, coef, flags, d_out);
}